// Round 17
// baseline (217.844 us; speedup 1.0000x reference)
//
#include <hip/hip_runtime.h>
#include <hip/hip_bf16.h>
#include <math.h>

typedef short bf16x8 __attribute__((ext_vector_type(8)));
typedef float f32x4  __attribute__((ext_vector_type(4)));
typedef unsigned int uint4v __attribute__((ext_vector_type(4)));

constexpr int B_=4, CIN=96, H_=256, W_=256, HID=192, C2=384;
constexpr int NPX = H_*W_;          // 65536 px per plane
#define PB 8
constexpr int HP = H_/PB, WP = W_/PB;

__device__ __forceinline__ ushort f2bf(float f) {
    __hip_bfloat16 h = __float2bfloat16(f);
    ushort u; __builtin_memcpy(&u, &h, 2); return u;
}
__device__ __forceinline__ float bf2f(ushort u) {
    __hip_bfloat16 h; __builtin_memcpy(&h, &u, 2); return __bfloat162float(h);
}
// extract channel sub (0=lo,1=hi) of a packed bf16-pair uint as float
__device__ __forceinline__ float extc(uint u, int sub) {
    uint w = sub ? (u & 0xffff0000u) : (u << 16);
    float f; __builtin_memcpy(&f, &w, 4); return f;
}

// Fast exact-erf GELU: A&S 7.1.26 rational approx, |err| <= ~2e-7 abs.
__device__ __forceinline__ float gelu_f(float x) {
    float u  = x * 0.70710678118654752f;
    float au = fabsf(u);
    float t  = __builtin_amdgcn_rcpf(fmaf(0.3275911f, au, 1.0f));
    float poly = t * fmaf(t, fmaf(t, fmaf(t, fmaf(t, 1.061405429f,
                     -1.453152027f), 1.421413741f), -0.284496736f),
                     0.254829592f);
    float e  = __builtin_amdgcn_exp2f(au * au * -1.4426950408889634f);
    float g  = fmaf(-poly, e, 1.0f);          // erf(|u|)
    float one_plus = 1.0f + copysignf(g, u);  // 1 + erf(u)
    return 0.5f * x * one_plus;
}

// ---------------------------------------------------------------------------
// prep_gate: per-channel 8x8 spatial gate kernel from fft_w (+identity flags).
// ---------------------------------------------------------------------------
__global__ void prep_gate(const float* __restrict__ fftw,
                          float* __restrict__ g, int* __restrict__ flags) {
    int c = blockIdx.x;
    int t = threadIdx.x;             // one wave
    int n1 = t >> 3, n2 = t & 7;
    const float* Wc = fftw + c * 40;
    const double ct[8] = {1.0, 0.70710678118654752, 0.0, -0.70710678118654752,
                          -1.0, -0.70710678118654752, 0.0, 0.70710678118654752};
    double acc = 0.0;
    for (int k1 = 0; k1 < 8; ++k1)
        for (int k2 = 0; k2 < 8; ++k2) {
            double geff;
            if (k2 == 0 || k2 == 4)
                geff = 0.5 * ((double)Wc[k1*5+k2] + (double)Wc[((8-k1)&7)*5+k2]);
            else if (k2 < 4) geff = (double)Wc[k1*5+k2];
            else             geff = (double)Wc[((8-k1)&7)*5 + (8-k2)];
            acc += geff * ct[(k1*n1 + k2*n2) & 7];
        }
    acc *= (1.0/64.0);
    g[c*64 + t] = (float)acc;
    double expect = (t == 0) ? 1.0 : 0.0;
    unsigned long long m = __ballot(fabs(acc - expect) <= 1e-6);
    if (t == 0) flags[c] = (m == 0xFFFFFFFFFFFFFFFFull) ? 1 : 0;
}

__global__ void reduce_flags(const int* __restrict__ flags,
                             int* __restrict__ allflag) {
    int t = threadIdx.x;             // 64
    int ok = 1;
    for (int j = t; j < C2; j += 64) ok &= flags[j];
    unsigned long long m = __ballot(ok != 0);
    if (t == 0) allflag[0] = (m == 0xFFFFFFFFFFFFFFFFull) ? 1 : 0;
}

// ---------------------------------------------------------------------------
// prep_fragw: build hi/lo weight pairs in MFMA A-fragment order.
// ---------------------------------------------------------------------------
__global__ void prep_fragw(const float* __restrict__ w_in,
                           const float* __restrict__ w_out,
                           ushort* __restrict__ wfin,
                           ushort* __restrict__ wfout) {
    int idx = blockIdx.x * 256 + threadIdx.x;
    if (idx < 72 * 64) {
        int f = idx >> 6, l = idx & 63;
        int wv = f / 9, rem = f % 9;
        int kc = rem / 3, mf = rem % 3;
        int row = wv*48 + mf*16 + (l & 15);
        int kb  = kc*32 + (l >> 4)*8;
        ushort* dst = wfin + (size_t)f*1024 + l*16;
#pragma unroll
        for (int j = 0; j < 8; ++j) {
            float v = w_in[(size_t)row*CIN + kb + j];
            ushort h = f2bf(v);
            dst[j]   = h;
            dst[8+j] = f2bf(v - bf2f(h));
        }
    }
    int jdx = idx - 72*64;
    if (jdx >= 0 && jdx < 36 * 64) {
        int f = jdx >> 6, l = jdx & 63;
        int ocg = f / 18, rem = f % 18;
        int kc = rem / 3, mf = rem % 3;
        int row = ocg*48 + mf*16 + (l & 15);
        int kb  = kc*32 + (l >> 4)*8;
        ushort* dst = wfout + (size_t)f*1024 + l*16;
#pragma unroll
        for (int j = 0; j < 8; ++j) {
            float v = w_out[(size_t)row*HID + kb + j];
            ushort h = f2bf(v);
            dst[j]   = h;
            dst[8+j] = f2bf(v - bf2f(h));
        }
    }
}

// ---------------------------------------------------------------------------
// A1 v8 (R13 best): GEMM1 via MFMA; coalesced staging (pitch 53 -> 2-way LDS
// writes), frag-ordered weights, two-phase LDS transpose store,
// row-interleaved z [row][cp 192][col 256]. z stores NONTEMPORAL (z can't be
// L2-resident anyway; keep L2 for x/weights).
// ---------------------------------------------------------------------------
__global__ __launch_bounds__(512)
void gemm1_mfma(const float* __restrict__ x,
                const ushort* __restrict__ wfin,
                uint* __restrict__ z4, int b0) {
    __shared__ uint lds[96*68];           // stage view [64][53]; zout view [96][68]
    int t = threadIdx.x;
    int l = t & 63, wv = t >> 6;          // 8 waves
    int lm = l & 15, g4 = l >> 4;
    int px0 = blockIdx.x * 64;
    int r0 = px0 >> 8, c0 = px0 & 255;    // image row / col base
    int bg = blockIdx.y;
    const float* xb = x + (size_t)(b0 + bg) * CIN * NPX;
    uint* zb = z4 + (size_t)bg * HID * NPX;

    // stage x -> LDS packed channel pairs [px][cp] (pitch 53)
    for (int i = t; i < 768; i += 512) {
        int cp = i >> 4;                  // 0..47 (channel pair)
        int q  = i & 15;                  // 0..15 (px quad)
        const float* pa = xb + (size_t)(2*cp) * NPX + px0 + 4*q;
        float4 a = *(const float4*)pa;
        float4 b = *(const float4*)(pa + NPX);
        lds[(4*q+0)*53 + cp] = (uint)f2bf(a.x) | ((uint)f2bf(b.x) << 16);
        lds[(4*q+1)*53 + cp] = (uint)f2bf(a.y) | ((uint)f2bf(b.y) << 16);
        lds[(4*q+2)*53 + cp] = (uint)f2bf(a.z) | ((uint)f2bf(b.z) << 16);
        lds[(4*q+3)*53 + cp] = (uint)f2bf(a.w) | ((uint)f2bf(b.w) << 16);
    }
    __syncthreads();

    f32x4 acc[3][4];
#pragma unroll
    for (int mf = 0; mf < 3; ++mf)
#pragma unroll
        for (int nf = 0; nf < 4; ++nf) acc[mf][nf] = (f32x4){0.f,0.f,0.f,0.f};

#pragma unroll
    for (int kc = 0; kc < 3; ++kc) {
        int cp0 = kc*16 + g4*4;
        bf16x8 bfr[4];
#pragma unroll
        for (int nf = 0; nf < 4; ++nf)
            bfr[nf] = *(const bf16x8*)&lds[(nf*16 + lm)*53 + cp0];
#pragma unroll
        for (int mf = 0; mf < 3; ++mf) {
            int f = wv*9 + kc*3 + mf;
            const ushort* wp = wfin + (size_t)f*1024 + l*16;
            bf16x8 ah = *(const bf16x8*)wp;
            bf16x8 al = *(const bf16x8*)(wp + 8);
#pragma unroll
            for (int nf = 0; nf < 4; ++nf) {
                acc[mf][nf] = __builtin_amdgcn_mfma_f32_16x16x32_bf16(ah, bfr[nf], acc[mf][nf], 0,0,0);
                acc[mf][nf] = __builtin_amdgcn_mfma_f32_16x16x32_bf16(al, bfr[nf], acc[mf][nf], 0,0,0);
            }
        }
    }

    // two-phase z transpose+store: phase ph covers pair-planes [96ph, 96ph+96)
#pragma unroll
    for (int ph = 0; ph < 2; ++ph) {
        __syncthreads();
        if ((wv >> 2) == ph) {
            int wl = wv & 3;
#pragma unroll
            for (int mf = 0; mf < 3; ++mf)
#pragma unroll
                for (int nf = 0; nf < 4; ++nf) {
                    int col = nf*16 + lm;
                    int lr  = wl*24 + mf*8 + g4*2;
                    lds[lr*68 + col]     = (uint)f2bf(acc[mf][nf][0]) |
                                           ((uint)f2bf(acc[mf][nf][1]) << 16);
                    lds[(lr+1)*68 + col] = (uint)f2bf(acc[mf][nf][2]) |
                                           ((uint)f2bf(acc[mf][nf][3]) << 16);
                }
        }
        __syncthreads();
        // coalesced z store, row-interleaved layout, nontemporal
#pragma unroll
        for (int i = 0; i < 3; ++i) {
            int idx = t + i*512;          // 1536 = 96 planes x 16 quads
            int lr = idx >> 4, q = idx & 15;
            uint4v v = *(const uint4v*)&lds[lr*68 + 4*q];
            __builtin_nontemporal_store(v,
                (uint4v*)(zb + ((size_t)r0*192 + ph*96 + lr) * 256 + c0 + 4*q));
        }
    }
}

// ---------------------------------------------------------------------------
// A2: spectral-gate fixup on packed z (row-interleaved). No-op when allflag.
// ---------------------------------------------------------------------------
__global__ __launch_bounds__(256)
void gate_fix(uint* __restrict__ z4, const float* __restrict__ g,
              const int* __restrict__ flags, const int* __restrict__ allflag) {
    if (allflag[0]) return;
    int pid = blockIdx.x;
    int bg = blockIdx.y;
    int ph = pid >> 5, pw = pid & 31;
    int t = threadIdx.x, l = t & 63, wv = t >> 6;
    int p1 = l >> 3, p2 = l & 7;
    uint* zb = z4 + (size_t)bg * HID * NPX;
    for (int cp = wv; cp < HID; cp += 4) {
        int f0 = flags[2*cp], f1 = flags[2*cp+1];
        if (f0 & f1) continue;
        const float* gc0 = g + (2*cp)*64;
        const float* gc1 = gc0 + 64;
        size_t zi = ((size_t)(ph*8 + p1) * 192 + cp) * 256 + pw*8 + p2;
        uint u = zb[zi];
        float v0 = extc(u, 0), v1 = extc(u, 1);
        float s0 = 0.f, s1 = 0.f;
        for (int q = 0; q < 64; ++q) {
            int idx = ((p1 - (q >> 3)) & 7)*8 + ((p2 - (q & 7)) & 7);
            s0 += __shfl(v0, q, 64) * gc0[idx];
            s1 += __shfl(v1, q, 64) * gc1[idx];
        }
        float r0 = f0 ? v0 : s0;
        float r1 = f1 ? v1 : s1;
        zb[zi] = (uint)f2bf(r0) | ((uint)f2bf(r1) << 16);
    }
}

// ---------------------------------------------------------------------------
// B1: barrier-free streaming depthwise 3x3 + GELU gating.
// z read and tg write both ROW-INTERLEAVED; tg stores nontemporal.
// Grid: (8 strip-groups, 96 [jg*4+pp], nb); block = 256 = 4 waves.
// ---------------------------------------------------------------------------
constexpr int DROWS = 8;
__global__ __launch_bounds__(256)
void dw_gelu6(const uint* __restrict__ z4, const float* __restrict__ w_dw,
              uint* __restrict__ tg4) {
    int t = threadIdx.x;
    int wv = t >> 6, lane = t & 63;
    int strip = blockIdx.x * 4 + wv;       // 0..31
    int s = blockIdx.y;                    // 0..95: jg = s>>2, pp = s&3
    int jg = s >> 2, pp = s & 3;
    int bg = blockIdx.z;
    int row0 = strip * DROWS;
    int cb = lane * 4;
    const uint* zb = z4 + (size_t)bg * HID * NPX;
    uint* tb = tg4 + (size_t)bg * HID/2 * NPX;

    int c  = jg*8 + pp*2;                  // z1 channels c, c+1 (plane p1)
    int p1 = c >> 1;
    int p2 = p1 + 96;                      // z2 channels c+192, c+193
    float wA[18], wB[18];
#pragma unroll
    for (int k = 0; k < 18; ++k) {
        wA[k] = w_dw[(size_t)c*9 + k];
        wB[k] = w_dw[(size_t)(c+HID)*9 + k];
    }

    float accA[2][2][4], accB[2][2][4];    // [src][sub][px]
#pragma unroll
    for (int sx = 0; sx < 2; ++sx)
#pragma unroll
        for (int u = 0; u < 2; ++u)
#pragma unroll
            for (int j = 0; j < 4; ++j) { accA[sx][u][j]=0.f; accB[sx][u][j]=0.f; }

    auto ld = [&](int r, uint4& A, uint4& B) {
        int y = row0 - 1 + r;
        A = (uint4){0,0,0,0}; B = (uint4){0,0,0,0};
        if (y >= 0 && y < H_) {
            A = *(const uint4*)(zb + ((size_t)y*192 + p1)*256 + cb);
            B = *(const uint4*)(zb + ((size_t)y*192 + p2)*256 + cb);
        }
    };

    uint4 a_cur, b_cur;
    ld(0, a_cur, b_cur);
#pragma unroll
    for (int r = 0; r < DROWS + 2; ++r) {
        uint4 a_nxt, b_nxt;
        if (r < DROWS + 1) ld(r + 1, a_nxt, b_nxt);

        uint aL = (uint)__shfl_up((int)a_cur.w, 1, 64);  if (lane == 0)  aL = 0u;
        uint aR = (uint)__shfl_down((int)a_cur.x, 1, 64); if (lane == 63) aR = 0u;
        uint bL = (uint)__shfl_up((int)b_cur.w, 1, 64);  if (lane == 0)  bL = 0u;
        uint bR = (uint)__shfl_down((int)b_cur.x, 1, 64); if (lane == 63) bR = 0u;

        float dA[2][4], dB[2][4];
#pragma unroll
        for (int sub = 0; sub < 2; ++sub) {
            {   // src A (z1)
                float xv[6] = {extc(aL,sub), extc(a_cur.x,sub), extc(a_cur.y,sub),
                               extc(a_cur.z,sub), extc(a_cur.w,sub), extc(aR,sub)};
                const float* w = &wA[sub*9];
#pragma unroll
                for (int j = 0; j < 4; ++j) {
                    float h2 = fmaf(xv[j],w[6], fmaf(xv[j+1],w[7], xv[j+2]*w[8]));
                    float h1 = fmaf(xv[j],w[3], fmaf(xv[j+1],w[4], xv[j+2]*w[5]));
                    float h0 = fmaf(xv[j],w[0], fmaf(xv[j+1],w[1], xv[j+2]*w[2]));
                    dA[sub][j]    = accA[0][sub][j] + h2;
                    accA[0][sub][j] = accB[0][sub][j] + h1;
                    accB[0][sub][j] = h0;
                }
            }
            {   // src B (z2)
                float xv[6] = {extc(bL,sub), extc(b_cur.x,sub), extc(b_cur.y,sub),
                               extc(b_cur.z,sub), extc(b_cur.w,sub), extc(bR,sub)};
                const float* w = &wB[sub*9];
#pragma unroll
                for (int j = 0; j < 4; ++j) {
                    float h2 = fmaf(xv[j],w[6], fmaf(xv[j+1],w[7], xv[j+2]*w[8]));
                    float h1 = fmaf(xv[j],w[3], fmaf(xv[j+1],w[4], xv[j+2]*w[5]));
                    float h0 = fmaf(xv[j],w[0], fmaf(xv[j+1],w[1], xv[j+2]*w[2]));
                    dB[sub][j]    = accA[1][sub][j] + h2;
                    accA[1][sub][j] = accB[1][sub][j] + h1;
                    accB[1][sub][j] = h0;
                }
            }
        }

        if (r >= 2) {
            int o = row0 + r - 2;
            uint4v val;
            val.x = (uint)f2bf(gelu_f(dA[0][0]) * dB[0][0]) |
                    (((uint)f2bf(gelu_f(dA[1][0]) * dB[1][0])) << 16);
            val.y = (uint)f2bf(gelu_f(dA[0][1]) * dB[0][1]) |
                    (((uint)f2bf(gelu_f(dA[1][1]) * dB[1][1])) << 16);
            val.z = (uint)f2bf(gelu_f(dA[0][2]) * dB[0][2]) |
                    (((uint)f2bf(gelu_f(dA[1][2]) * dB[1][2])) << 16);
            val.w = (uint)f2bf(gelu_f(dA[0][3]) * dB[0][3]) |
                    (((uint)f2bf(gelu_f(dA[1][3]) * dB[1][3])) << 16);
            __builtin_nontemporal_store(val,
                (uint4v*)(tb + ((size_t)o*96 + s)*256 + cb));
        }
        a_cur = a_nxt; b_cur = b_nxt;
    }
}

// ---------------------------------------------------------------------------
// B2 v4: GEMM2 via MFMA; frag-ordered weights; row-interleaved tg; out via
// per-mf LDS transpose with NONTEMPORAL 1KB-coalesced stores.
// Block: 512 thr / 8 waves (2 ocg x 4 pxg); grid (256 rows, 1, nb).
// ---------------------------------------------------------------------------
__global__ __launch_bounds__(512)
void gemm2_mfma(const uint* __restrict__ tg4,
                const ushort* __restrict__ wfout,
                float* __restrict__ out, int b0) {
    __shared__ float os[32][260];
    int t = threadIdx.x;
    int l = t & 63, wv = t >> 6;          // 8 waves
    int ocg = wv & 1, pxg = wv >> 1;      // 2 oc halves x 4 px groups
    int lm = l & 15, g4 = l >> 4;
    int h = blockIdx.x;
    int bg = blockIdx.z;
    const uint* tb = tg4 + (size_t)bg * HID/2 * NPX;

    f32x4 acc[3][4];
#pragma unroll
    for (int mf = 0; mf < 3; ++mf)
#pragma unroll
        for (int nf = 0; nf < 4; ++nf) acc[mf][nf] = (f32x4){0.f,0.f,0.f,0.f};

#pragma unroll
    for (int kc = 0; kc < 6; ++kc) {
        int s0 = kc*16 + g4*4;
        bf16x8 bfr[4];
#pragma unroll
        for (int nf = 0; nf < 4; ++nf) {
            int col = pxg*64 + nf*16 + lm;
            uint4 u;
            u.x = tb[((size_t)h*96 + s0+0)*256 + col];
            u.y = tb[((size_t)h*96 + s0+1)*256 + col];
            u.z = tb[((size_t)h*96 + s0+2)*256 + col];
            u.w = tb[((size_t)h*96 + s0+3)*256 + col];
            bf16x8 v; __builtin_memcpy(&v, &u, 16);
            bfr[nf] = v;
        }
#pragma unroll
        for (int mf = 0; mf < 3; ++mf) {
            int f = ocg*18 + kc*3 + mf;
            const ushort* wp = wfout + (size_t)f*1024 + l*16;
            bf16x8 ah = *(const bf16x8*)wp;
            bf16x8 al = *(const bf16x8*)(wp + 8);
#pragma unroll
            for (int nf = 0; nf < 4; ++nf) {
                acc[mf][nf] = __builtin_amdgcn_mfma_f32_16x16x32_bf16(ah, bfr[nf], acc[mf][nf], 0,0,0);
                acc[mf][nf] = __builtin_amdgcn_mfma_f32_16x16x32_bf16(al, bfr[nf], acc[mf][nf], 0,0,0);
            }
        }
    }
    float* ob = out + (size_t)(b0 + bg) * CIN * NPX;
#pragma unroll
    for (int mf = 0; mf < 3; ++mf) {
        if (mf) __syncthreads();
#pragma unroll
        for (int nf = 0; nf < 4; ++nf) {
            int col = pxg*64 + nf*16 + lm;
#pragma unroll
            for (int r = 0; r < 4; ++r)
                os[ocg*16 + g4*4 + r][col] = acc[mf][nf][r];
        }
        __syncthreads();
#pragma unroll
        for (int ri = 0; ri < 4; ++ri) {
            int idx = t + ri*512;         // 2048 = 32 rows x 64 lanes
            int ro = idx >> 6, l4 = idx & 63;
            int oc = mf*16 + (ro & 15) + (ro >> 4)*48;
            f32x4 v = *(const f32x4*)&os[ro][l4*4];
            __builtin_nontemporal_store(v,
                (f32x4*)(ob + (size_t)oc*NPX + (size_t)h*W_ + l4*4));
        }
    }
}

// ---------------------------------------------------------------------------
extern "C" void kernel_launch(void* const* d_in, const int* in_sizes, int n_in,
                              void* d_out, int out_size, void* d_ws, size_t ws_size,
                              hipStream_t stream) {
    const float* x     = (const float*)d_in[0];
    const float* w_in  = (const float*)d_in[1];
    const float* w_dw  = (const float*)d_in[2];
    const float* fftw  = (const float*)d_in[3];
    const float* w_out = (const float*)d_in[4];
    float* out = (float*)d_out;

    char* ws = (char*)d_ws;
    ushort* wfin   = (ushort*)(ws + 0);        // 147456 (72 frags x 64 x 16)
    ushort* wfout  = (ushort*)(ws + 147456);   //  73728 (36 frags x 64 x 16)
    float*  g      = (float*) (ws + 221184);   //  98304
    int*    flags  = (int*)   (ws + 319488);   //   1536
    int*    allflag= (int*)   (ws + 321024);   //      4

    const size_t zoff   = 327680;
    const size_t zbytes = (size_t)HID * NPX * 4;     // 50331648 per batch
    const size_t tbytes = (size_t)(HID/2) * NPX * 4; // 25165824 per batch
    size_t avail = (ws_size > zoff) ? ws_size - zoff : 0;
    int nbg = (int)(avail / (zbytes + tbytes));
    if (nbg < 1) nbg = 1;
    if (nbg > 2) nbg = 2;   // keep z (96 MiB) + x slice L3-resident
    uint* z4  = (uint*)(ws + zoff);
    uint* tg4 = (uint*)(ws + zoff + (size_t)nbg * zbytes);

    prep_gate<<<dim3(C2), dim3(64), 0, stream>>>(fftw, g, flags);
    reduce_flags<<<dim3(1), dim3(64), 0, stream>>>(flags, allflag);
    prep_fragw<<<dim3(27), dim3(256), 0, stream>>>(w_in, w_out, wfin, wfout);

    for (int b0 = 0; b0 < B_; b0 += nbg) {
        int nb = (B_ - b0 < nbg) ? (B_ - b0) : nbg;
        gemm1_mfma<<<dim3(NPX/64, nb), dim3(512), 0, stream>>>(x, wfin, z4, b0);
        gate_fix<<<dim3(HP*WP, nb), dim3(256), 0, stream>>>(z4, g, flags, allflag);
        dw_gelu6<<<dim3(H_/DROWS/4, 96, nb), dim3(256), 0, stream>>>(z4, w_dw, tg4);
        gemm2_mfma<<<dim3(H_, 1, nb), dim3(512), 0, stream>>>(tg4, wfout, out, b0);
    }
}

// Round 18
// 191.549 us; speedup vs baseline: 1.1373x; 1.1373x over previous
//
#include <hip/hip_runtime.h>
#include <hip/hip_bf16.h>
#include <math.h>

typedef short bf16x8 __attribute__((ext_vector_type(8)));
typedef float f32x4  __attribute__((ext_vector_type(4)));

constexpr int B_=4, CIN=96, H_=256, W_=256, HID=192, C2=384;
constexpr int NPX = H_*W_;          // 65536 px per plane
#define PB 8
constexpr int HP = H_/PB, WP = W_/PB;

__device__ __forceinline__ ushort f2bf(float f) {
    __hip_bfloat16 h = __float2bfloat16(f);
    ushort u; __builtin_memcpy(&u, &h, 2); return u;
}
__device__ __forceinline__ float bf2f(ushort u) {
    __hip_bfloat16 h; __builtin_memcpy(&h, &u, 2); return __bfloat162float(h);
}
// extract channel sub (0=lo,1=hi) of a packed bf16-pair uint as float
__device__ __forceinline__ float extc(uint u, int sub) {
    uint w = sub ? (u & 0xffff0000u) : (u << 16);
    float f; __builtin_memcpy(&f, &w, 4); return f;
}

// Fast exact-erf GELU: A&S 7.1.26 rational approx, |err| <= ~2e-7 abs.
__device__ __forceinline__ float gelu_f(float x) {
    float u  = x * 0.70710678118654752f;
    float au = fabsf(u);
    float t  = __builtin_amdgcn_rcpf(fmaf(0.3275911f, au, 1.0f));
    float poly = t * fmaf(t, fmaf(t, fmaf(t, fmaf(t, 1.061405429f,
                     -1.453152027f), 1.421413741f), -0.284496736f),
                     0.254829592f);
    float e  = __builtin_amdgcn_exp2f(au * au * -1.4426950408889634f);
    float g  = fmaf(-poly, e, 1.0f);          // erf(|u|)
    float one_plus = 1.0f + copysignf(g, u);  // 1 + erf(u)
    return 0.5f * x * one_plus;
}

// ---------------------------------------------------------------------------
// prep_gate: per-channel 8x8 spatial gate kernel from fft_w (+identity flags).
// ---------------------------------------------------------------------------
__global__ void prep_gate(const float* __restrict__ fftw,
                          float* __restrict__ g, int* __restrict__ flags) {
    int c = blockIdx.x;
    int t = threadIdx.x;             // one wave
    int n1 = t >> 3, n2 = t & 7;
    const float* Wc = fftw + c * 40;
    const double ct[8] = {1.0, 0.70710678118654752, 0.0, -0.70710678118654752,
                          -1.0, -0.70710678118654752, 0.0, 0.70710678118654752};
    double acc = 0.0;
    for (int k1 = 0; k1 < 8; ++k1)
        for (int k2 = 0; k2 < 8; ++k2) {
            double geff;
            if (k2 == 0 || k2 == 4)
                geff = 0.5 * ((double)Wc[k1*5+k2] + (double)Wc[((8-k1)&7)*5+k2]);
            else if (k2 < 4) geff = (double)Wc[k1*5+k2];
            else             geff = (double)Wc[((8-k1)&7)*5 + (8-k2)];
            acc += geff * ct[(k1*n1 + k2*n2) & 7];
        }
    acc *= (1.0/64.0);
    g[c*64 + t] = (float)acc;
    double expect = (t == 0) ? 1.0 : 0.0;
    unsigned long long m = __ballot(fabs(acc - expect) <= 1e-6);
    if (t == 0) flags[c] = (m == 0xFFFFFFFFFFFFFFFFull) ? 1 : 0;
}

__global__ void reduce_flags(const int* __restrict__ flags,
                             int* __restrict__ allflag) {
    int t = threadIdx.x;             // 64
    int ok = 1;
    for (int j = t; j < C2; j += 64) ok &= flags[j];
    unsigned long long m = __ballot(ok != 0);
    if (t == 0) allflag[0] = (m == 0xFFFFFFFFFFFFFFFFull) ? 1 : 0;
}

// ---------------------------------------------------------------------------
// prep_fragw: build hi/lo weight pairs in MFMA A-fragment order.
// ---------------------------------------------------------------------------
__global__ void prep_fragw(const float* __restrict__ w_in,
                           const float* __restrict__ w_out,
                           ushort* __restrict__ wfin,
                           ushort* __restrict__ wfout) {
    int idx = blockIdx.x * 256 + threadIdx.x;
    if (idx < 72 * 64) {
        int f = idx >> 6, l = idx & 63;
        int wv = f / 9, rem = f % 9;
        int kc = rem / 3, mf = rem % 3;
        int row = wv*48 + mf*16 + (l & 15);
        int kb  = kc*32 + (l >> 4)*8;
        ushort* dst = wfin + (size_t)f*1024 + l*16;
#pragma unroll
        for (int j = 0; j < 8; ++j) {
            float v = w_in[(size_t)row*CIN + kb + j];
            ushort h = f2bf(v);
            dst[j]   = h;
            dst[8+j] = f2bf(v - bf2f(h));
        }
    }
    int jdx = idx - 72*64;
    if (jdx >= 0 && jdx < 36 * 64) {
        int f = jdx >> 6, l = jdx & 63;
        int ocg = f / 18, rem = f % 18;
        int kc = rem / 3, mf = rem % 3;
        int row = ocg*48 + mf*16 + (l & 15);
        int kb  = kc*32 + (l >> 4)*8;
        ushort* dst = wfout + (size_t)f*1024 + l*16;
#pragma unroll
        for (int j = 0; j < 8; ++j) {
            float v = w_out[(size_t)row*HID + kb + j];
            ushort h = f2bf(v);
            dst[j]   = h;
            dst[8+j] = f2bf(v - bf2f(h));
        }
    }
}

// ---------------------------------------------------------------------------
// A1 v8 (R13 best): GEMM1 via MFMA; coalesced staging (pitch 53 -> 2-way LDS
// writes), frag-ordered weights, two-phase LDS transpose store,
// row-interleaved z [row][cp 192][col 256]. Regular (cached) z stores so z
// stays L3-resident for dw/gemm2 (NT stores here cost +26 us, R17).
// ---------------------------------------------------------------------------
__global__ __launch_bounds__(512)
void gemm1_mfma(const float* __restrict__ x,
                const ushort* __restrict__ wfin,
                uint* __restrict__ z4, int b0) {
    __shared__ uint lds[96*68];           // stage view [64][53]; zout view [96][68]
    int t = threadIdx.x;
    int l = t & 63, wv = t >> 6;          // 8 waves
    int lm = l & 15, g4 = l >> 4;
    int px0 = blockIdx.x * 64;
    int r0 = px0 >> 8, c0 = px0 & 255;    // image row / col base
    int bg = blockIdx.y;
    const float* xb = x + (size_t)(b0 + bg) * CIN * NPX;
    uint* zb = z4 + (size_t)bg * HID * NPX;

    // stage x -> LDS packed channel pairs [px][cp] (pitch 53: Δq bank
    // stride 20 -> 2-way write conflicts instead of 8-way at pitch 52)
    for (int i = t; i < 768; i += 512) {
        int cp = i >> 4;                  // 0..47 (channel pair)
        int q  = i & 15;                  // 0..15 (px quad)
        const float* pa = xb + (size_t)(2*cp) * NPX + px0 + 4*q;
        float4 a = *(const float4*)pa;
        float4 b = *(const float4*)(pa + NPX);
        lds[(4*q+0)*53 + cp] = (uint)f2bf(a.x) | ((uint)f2bf(b.x) << 16);
        lds[(4*q+1)*53 + cp] = (uint)f2bf(a.y) | ((uint)f2bf(b.y) << 16);
        lds[(4*q+2)*53 + cp] = (uint)f2bf(a.z) | ((uint)f2bf(b.z) << 16);
        lds[(4*q+3)*53 + cp] = (uint)f2bf(a.w) | ((uint)f2bf(b.w) << 16);
    }
    __syncthreads();

    f32x4 acc[3][4];
#pragma unroll
    for (int mf = 0; mf < 3; ++mf)
#pragma unroll
        for (int nf = 0; nf < 4; ++nf) acc[mf][nf] = (f32x4){0.f,0.f,0.f,0.f};

#pragma unroll
    for (int kc = 0; kc < 3; ++kc) {
        int cp0 = kc*16 + g4*4;
        bf16x8 bfr[4];
#pragma unroll
        for (int nf = 0; nf < 4; ++nf)
            bfr[nf] = *(const bf16x8*)&lds[(nf*16 + lm)*53 + cp0];
#pragma unroll
        for (int mf = 0; mf < 3; ++mf) {
            int f = wv*9 + kc*3 + mf;
            const ushort* wp = wfin + (size_t)f*1024 + l*16;
            bf16x8 ah = *(const bf16x8*)wp;
            bf16x8 al = *(const bf16x8*)(wp + 8);
#pragma unroll
            for (int nf = 0; nf < 4; ++nf) {
                acc[mf][nf] = __builtin_amdgcn_mfma_f32_16x16x32_bf16(ah, bfr[nf], acc[mf][nf], 0,0,0);
                acc[mf][nf] = __builtin_amdgcn_mfma_f32_16x16x32_bf16(al, bfr[nf], acc[mf][nf], 0,0,0);
            }
        }
    }

    // two-phase z transpose+store: phase ph covers pair-planes [96ph, 96ph+96)
#pragma unroll
    for (int ph = 0; ph < 2; ++ph) {
        __syncthreads();
        if ((wv >> 2) == ph) {
            int wl = wv & 3;
#pragma unroll
            for (int mf = 0; mf < 3; ++mf)
#pragma unroll
                for (int nf = 0; nf < 4; ++nf) {
                    int col = nf*16 + lm;
                    int lr  = wl*24 + mf*8 + g4*2;
                    lds[lr*68 + col]     = (uint)f2bf(acc[mf][nf][0]) |
                                           ((uint)f2bf(acc[mf][nf][1]) << 16);
                    lds[(lr+1)*68 + col] = (uint)f2bf(acc[mf][nf][2]) |
                                           ((uint)f2bf(acc[mf][nf][3]) << 16);
                }
        }
        __syncthreads();
        // coalesced z store, row-interleaved layout
#pragma unroll
        for (int i = 0; i < 3; ++i) {
            int idx = t + i*512;          // 1536 = 96 planes x 16 quads
            int lr = idx >> 4, q = idx & 15;
            uint4 v = *(const uint4*)&lds[lr*68 + 4*q];
            *(uint4*)(zb + ((size_t)r0*192 + ph*96 + lr) * 256 + c0 + 4*q) = v;
        }
    }
}

// ---------------------------------------------------------------------------
// A2: spectral-gate fixup on packed z (row-interleaved). No-op when allflag.
// ---------------------------------------------------------------------------
__global__ __launch_bounds__(256)
void gate_fix(uint* __restrict__ z4, const float* __restrict__ g,
              const int* __restrict__ flags, const int* __restrict__ allflag) {
    if (allflag[0]) return;
    int pid = blockIdx.x;
    int bg = blockIdx.y;
    int ph = pid >> 5, pw = pid & 31;
    int t = threadIdx.x, l = t & 63, wv = t >> 6;
    int p1 = l >> 3, p2 = l & 7;
    uint* zb = z4 + (size_t)bg * HID * NPX;
    for (int cp = wv; cp < HID; cp += 4) {
        int f0 = flags[2*cp], f1 = flags[2*cp+1];
        if (f0 & f1) continue;
        const float* gc0 = g + (2*cp)*64;
        const float* gc1 = gc0 + 64;
        size_t zi = ((size_t)(ph*8 + p1) * 192 + cp) * 256 + pw*8 + p2;
        uint u = zb[zi];
        float v0 = extc(u, 0), v1 = extc(u, 1);
        float s0 = 0.f, s1 = 0.f;
        for (int q = 0; q < 64; ++q) {
            int idx = ((p1 - (q >> 3)) & 7)*8 + ((p2 - (q & 7)) & 7);
            s0 += __shfl(v0, q, 64) * gc0[idx];
            s1 += __shfl(v1, q, 64) * gc1[idx];
        }
        float r0 = f0 ? v0 : s0;
        float r1 = f1 ? v1 : s1;
        zb[zi] = (uint)f2bf(r0) | ((uint)f2bf(r1) << 16);
    }
}

// ---------------------------------------------------------------------------
// B1: barrier-free streaming depthwise 3x3 + GELU gating.
// z read and tg write both in ROW-INTERLEAVED layouts (regular stores).
// Grid: (8 strip-groups, 96 [jg*4+pp], nb); block = 256 = 4 waves.
// ---------------------------------------------------------------------------
constexpr int DROWS = 8;
__global__ __launch_bounds__(256)
void dw_gelu6(const uint* __restrict__ z4, const float* __restrict__ w_dw,
              uint* __restrict__ tg4) {
    int t = threadIdx.x;
    int wv = t >> 6, lane = t & 63;
    int strip = blockIdx.x * 4 + wv;       // 0..31
    int s = blockIdx.y;                    // 0..95: jg = s>>2, pp = s&3
    int jg = s >> 2, pp = s & 3;
    int bg = blockIdx.z;
    int row0 = strip * DROWS;
    int cb = lane * 4;
    const uint* zb = z4 + (size_t)bg * HID * NPX;
    uint* tb = tg4 + (size_t)bg * HID/2 * NPX;

    int c  = jg*8 + pp*2;                  // z1 channels c, c+1 (plane p1)
    int p1 = c >> 1;
    int p2 = p1 + 96;                      // z2 channels c+192, c+193
    float wA[18], wB[18];
#pragma unroll
    for (int k = 0; k < 18; ++k) {
        wA[k] = w_dw[(size_t)c*9 + k];
        wB[k] = w_dw[(size_t)(c+HID)*9 + k];
    }

    float accA[2][2][4], accB[2][2][4];    // [src][sub][px]
#pragma unroll
    for (int sx = 0; sx < 2; ++sx)
#pragma unroll
        for (int u = 0; u < 2; ++u)
#pragma unroll
            for (int j = 0; j < 4; ++j) { accA[sx][u][j]=0.f; accB[sx][u][j]=0.f; }

    auto ld = [&](int r, uint4& A, uint4& B) {
        int y = row0 - 1 + r;
        A = (uint4){0,0,0,0}; B = (uint4){0,0,0,0};
        if (y >= 0 && y < H_) {
            A = *(const uint4*)(zb + ((size_t)y*192 + p1)*256 + cb);
            B = *(const uint4*)(zb + ((size_t)y*192 + p2)*256 + cb);
        }
    };

    uint4 a_cur, b_cur;
    ld(0, a_cur, b_cur);
#pragma unroll
    for (int r = 0; r < DROWS + 2; ++r) {
        uint4 a_nxt, b_nxt;
        if (r < DROWS + 1) ld(r + 1, a_nxt, b_nxt);

        uint aL = (uint)__shfl_up((int)a_cur.w, 1, 64);  if (lane == 0)  aL = 0u;
        uint aR = (uint)__shfl_down((int)a_cur.x, 1, 64); if (lane == 63) aR = 0u;
        uint bL = (uint)__shfl_up((int)b_cur.w, 1, 64);  if (lane == 0)  bL = 0u;
        uint bR = (uint)__shfl_down((int)b_cur.x, 1, 64); if (lane == 63) bR = 0u;

        float dA[2][4], dB[2][4];
#pragma unroll
        for (int sub = 0; sub < 2; ++sub) {
            {   // src A (z1)
                float xv[6] = {extc(aL,sub), extc(a_cur.x,sub), extc(a_cur.y,sub),
                               extc(a_cur.z,sub), extc(a_cur.w,sub), extc(aR,sub)};
                const float* w = &wA[sub*9];
#pragma unroll
                for (int j = 0; j < 4; ++j) {
                    float h2 = fmaf(xv[j],w[6], fmaf(xv[j+1],w[7], xv[j+2]*w[8]));
                    float h1 = fmaf(xv[j],w[3], fmaf(xv[j+1],w[4], xv[j+2]*w[5]));
                    float h0 = fmaf(xv[j],w[0], fmaf(xv[j+1],w[1], xv[j+2]*w[2]));
                    dA[sub][j]    = accA[0][sub][j] + h2;
                    accA[0][sub][j] = accB[0][sub][j] + h1;
                    accB[0][sub][j] = h0;
                }
            }
            {   // src B (z2)
                float xv[6] = {extc(bL,sub), extc(b_cur.x,sub), extc(b_cur.y,sub),
                               extc(b_cur.z,sub), extc(b_cur.w,sub), extc(bR,sub)};
                const float* w = &wB[sub*9];
#pragma unroll
                for (int j = 0; j < 4; ++j) {
                    float h2 = fmaf(xv[j],w[6], fmaf(xv[j+1],w[7], xv[j+2]*w[8]));
                    float h1 = fmaf(xv[j],w[3], fmaf(xv[j+1],w[4], xv[j+2]*w[5]));
                    float h0 = fmaf(xv[j],w[0], fmaf(xv[j+1],w[1], xv[j+2]*w[2]));
                    dB[sub][j]    = accA[1][sub][j] + h2;
                    accA[1][sub][j] = accB[1][sub][j] + h1;
                    accB[1][sub][j] = h0;
                }
            }
        }

        if (r >= 2) {
            int o = row0 + r - 2;
            uint4 val;
            val.x = (uint)f2bf(gelu_f(dA[0][0]) * dB[0][0]) |
                    (((uint)f2bf(gelu_f(dA[1][0]) * dB[1][0])) << 16);
            val.y = (uint)f2bf(gelu_f(dA[0][1]) * dB[0][1]) |
                    (((uint)f2bf(gelu_f(dA[1][1]) * dB[1][1])) << 16);
            val.z = (uint)f2bf(gelu_f(dA[0][2]) * dB[0][2]) |
                    (((uint)f2bf(gelu_f(dA[1][2]) * dB[1][2])) << 16);
            val.w = (uint)f2bf(gelu_f(dA[0][3]) * dB[0][3]) |
                    (((uint)f2bf(gelu_f(dA[1][3]) * dB[1][3])) << 16);
            *(uint4*)(tb + ((size_t)o*96 + s)*256 + cb) = val;
        }
        a_cur = a_nxt; b_cur = b_nxt;
    }
}

// ---------------------------------------------------------------------------
// B2 v4: GEMM2 via MFMA; frag-ordered weights; row-interleaved tg; out via
// per-mf LDS transpose with NONTEMPORAL 1KB-coalesced stores (out is never
// re-read, NT here is safe and was part of the 192 us best).
// Block: 512 thr / 8 waves (2 ocg x 4 pxg); grid (256 rows, 1, nb).
// ---------------------------------------------------------------------------
__global__ __launch_bounds__(512)
void gemm2_mfma(const uint* __restrict__ tg4,
                const ushort* __restrict__ wfout,
                float* __restrict__ out, int b0) {
    __shared__ float os[32][260];
    int t = threadIdx.x;
    int l = t & 63, wv = t >> 6;          // 8 waves
    int ocg = wv & 1, pxg = wv >> 1;      // 2 oc halves x 4 px groups
    int lm = l & 15, g4 = l >> 4;
    int h = blockIdx.x;
    int bg = blockIdx.z;
    const uint* tb = tg4 + (size_t)bg * HID/2 * NPX;

    f32x4 acc[3][4];
#pragma unroll
    for (int mf = 0; mf < 3; ++mf)
#pragma unroll
        for (int nf = 0; nf < 4; ++nf) acc[mf][nf] = (f32x4){0.f,0.f,0.f,0.f};

#pragma unroll
    for (int kc = 0; kc < 6; ++kc) {
        int s0 = kc*16 + g4*4;
        bf16x8 bfr[4];
#pragma unroll
        for (int nf = 0; nf < 4; ++nf) {
            int col = pxg*64 + nf*16 + lm;
            uint4 u;
            u.x = tb[((size_t)h*96 + s0+0)*256 + col];
            u.y = tb[((size_t)h*96 + s0+1)*256 + col];
            u.z = tb[((size_t)h*96 + s0+2)*256 + col];
            u.w = tb[((size_t)h*96 + s0+3)*256 + col];
            bf16x8 v; __builtin_memcpy(&v, &u, 16);
            bfr[nf] = v;
        }
#pragma unroll
        for (int mf = 0; mf < 3; ++mf) {
            int f = ocg*18 + kc*3 + mf;
            const ushort* wp = wfout + (size_t)f*1024 + l*16;
            bf16x8 ah = *(const bf16x8*)wp;
            bf16x8 al = *(const bf16x8*)(wp + 8);
#pragma unroll
            for (int nf = 0; nf < 4; ++nf) {
                acc[mf][nf] = __builtin_amdgcn_mfma_f32_16x16x32_bf16(ah, bfr[nf], acc[mf][nf], 0,0,0);
                acc[mf][nf] = __builtin_amdgcn_mfma_f32_16x16x32_bf16(al, bfr[nf], acc[mf][nf], 0,0,0);
            }
        }
    }
    float* ob = out + (size_t)(b0 + bg) * CIN * NPX;
#pragma unroll
    for (int mf = 0; mf < 3; ++mf) {
        if (mf) __syncthreads();
#pragma unroll
        for (int nf = 0; nf < 4; ++nf) {
            int col = pxg*64 + nf*16 + lm;
#pragma unroll
            for (int r = 0; r < 4; ++r)
                os[ocg*16 + g4*4 + r][col] = acc[mf][nf][r];
        }
        __syncthreads();
#pragma unroll
        for (int ri = 0; ri < 4; ++ri) {
            int idx = t + ri*512;         // 2048 = 32 rows x 64 lanes
            int ro = idx >> 6, l4 = idx & 63;
            int oc = mf*16 + (ro & 15) + (ro >> 4)*48;
            f32x4 v = *(const f32x4*)&os[ro][l4*4];
            __builtin_nontemporal_store(v,
                (f32x4*)(ob + (size_t)oc*NPX + (size_t)h*W_ + l4*4));
        }
    }
}

// ---------------------------------------------------------------------------
extern "C" void kernel_launch(void* const* d_in, const int* in_sizes, int n_in,
                              void* d_out, int out_size, void* d_ws, size_t ws_size,
                              hipStream_t stream) {
    const float* x     = (const float*)d_in[0];
    const float* w_in  = (const float*)d_in[1];
    const float* w_dw  = (const float*)d_in[2];
    const float* fftw  = (const float*)d_in[3];
    const float* w_out = (const float*)d_in[4];
    float* out = (float*)d_out;

    char* ws = (char*)d_ws;
    ushort* wfin   = (ushort*)(ws + 0);        // 147456 (72 frags x 64 x 16)
    ushort* wfout  = (ushort*)(ws + 147456);   //  73728 (36 frags x 64 x 16)
    float*  g      = (float*) (ws + 221184);   //  98304
    int*    flags  = (int*)   (ws + 319488);   //   1536
    int*    allflag= (int*)   (ws + 321024);   //      4

    const size_t zoff   = 327680;
    const size_t zbytes = (size_t)HID * NPX * 4;     // 50331648 per batch
    const size_t tbytes = (size_t)(HID/2) * NPX * 4; // 25165824 per batch
    size_t avail = (ws_size > zoff) ? ws_size - zoff : 0;
    int nbg = (int)(avail / (zbytes + tbytes));
    if (nbg < 1) nbg = 1;
    if (nbg > 2) nbg = 2;   // keep z (96 MiB) + x slice L3-resident
    uint* z4  = (uint*)(ws + zoff);
    uint* tg4 = (uint*)(ws + zoff + (size_t)nbg * zbytes);

    prep_gate<<<dim3(C2), dim3(64), 0, stream>>>(fftw, g, flags);
    reduce_flags<<<dim3(1), dim3(64), 0, stream>>>(flags, allflag);
    prep_fragw<<<dim3(27), dim3(256), 0, stream>>>(w_in, w_out, wfin, wfout);

    for (int b0 = 0; b0 < B_; b0 += nbg) {
        int nb = (B_ - b0 < nbg) ? (B_ - b0) : nbg;
        gemm1_mfma<<<dim3(NPX/64, nb), dim3(512), 0, stream>>>(x, wfin, z4, b0);
        gate_fix<<<dim3(HP*WP, nb), dim3(256), 0, stream>>>(z4, g, flags, allflag);
        dw_gelu6<<<dim3(H_/DROWS/4, 96, nb), dim3(256), 0, stream>>>(z4, w_dw, tg4);
        gemm2_mfma<<<dim3(H_, 1, nb), dim3(512), 0, stream>>>(tg4, wfout, out, b0);
    }
}